// Round 10
// baseline (197.006 us; speedup 1.0000x reference)
//
#include <hip/hip_runtime.h>
#include <math.h>

#define BATCH 16
#define TSTEPS 128
#define UNITS 64
#define FEAT 512
#define FLAT 3136
#define OUTROW 576           // 512 + 64
#define OUT_FEATS (BATCH * TSTEPS * OUTROW)   // 1179648
#define MEMN 16
#define NIMG 2048

typedef short bf16x8 __attribute__((ext_vector_type(8)));
typedef short short4v __attribute__((ext_vector_type(4)));
typedef float f32x4 __attribute__((ext_vector_type(4)));

__device__ __forceinline__ short f2b(float f) {
    unsigned u = __float_as_uint(f);
    unsigned r = (u + 0x7FFFu + ((u >> 16) & 1u)) >> 16;
    return (short)r;
}

// ---------------- mega-pack: all weight matrices fp32 [K][N] -> bf16 [K/8][N][8]
// (coalesced via LDS transpose) + seg precompute as the last block.
__global__ __launch_bounds__(256) void megapack(
    const float* __restrict__ dw, const float* __restrict__ gk,
    const float* __restrict__ c1w, const float* __restrict__ c2w,
    const float* __restrict__ c3w,
    short* __restrict__ wpd, short* __restrict__ wpg, short* __restrict__ wp1,
    short* __restrict__ wp2, short* __restrict__ wp3,
    const int* __restrict__ dones, const int* __restrict__ step0,
    int* __restrict__ seg, int* __restrict__ nseg, float* __restrict__ out)
{
    __shared__ float lds[8 * 513];         // 16.4 KB, pad 513 -> conflict-free
    const int blk = blockIdx.x;
    const int tid = threadIdx.x;

    const float* src; short* dst; int N, kg;
    if (blk < 392)      { src = dw;  dst = wpd; N = 512; kg = blk; }
    else if (blk < 456) { src = gk;  dst = wpg; N = 192; kg = blk - 392; }
    else if (blk < 488) { src = c1w; dst = wp1; N = 32;  kg = blk - 456; }
    else if (blk < 552) { src = c2w; dst = wp2; N = 64;  kg = blk - 488; }
    else if (blk < 624) { src = c3w; dst = wp3; N = 64;  kg = blk - 552; }
    else {
        // segment precompute: step dynamics depend only on dones/step0
        const int b = tid;
        if (b < BATCH) {
            int step = step0[b];
            int n = 0, start = 0;
            for (int t = 0; t < TSTEPS; ++t) {
                step += 1;
                const int reset = (dones[b * TSTEPS + t] == 1) || ((step % MEMN) == 0);
                if (reset) step = 0;
                if (reset || t == TSTEPS - 1) {
                    seg[b * TSTEPS + n] = start | ((t - start + 1) << 8) | (reset << 16);
                    n += 1;
                    start = t + 1;
                }
            }
            nseg[b] = n;
            out[OUT_FEATS + 1024 + b] = (float)step;
        }
        return;
    }

#pragma unroll
    for (int j = 0; j < 8; ++j)
        for (int n = tid; n < N; n += 256)
            lds[j * 513 + n] = src[(size_t)(kg * 8 + j) * N + n];
    __syncthreads();
    short* d = dst + (size_t)kg * N * 8;
    for (int t = tid; t < N * 8; t += 256) {
        int n = t >> 3, j = t & 7;
        d[t] = f2b(lds[j * 513 + n]);
    }
}

// ---------------- fused conv tower: in [n,84,84,4] fp32 -> out [n,3136] bf16
// One block per image, 256 thr = 4 waves, 38.1 KB LDS -> 4 blocks/CU.
// LDS-traffic-halved layout: each wave owns 2 n-tiles in registers (read A
// once -> 2 MFMAs); waves split over m. conv1: 7 phases x 4 m-tiles (1/wave),
// 20-row slab + register prefetch pipeline. conv2/conv3: n-pair x m-half waves.
__global__ __launch_bounds__(256, 4) void convtower_mfma(
    const float* __restrict__ in,
    const short* __restrict__ wp1, const float* __restrict__ b1,
    const short* __restrict__ wp2, const float* __restrict__ b2,
    const short* __restrict__ wp3, const float* __restrict__ b3,
    short* __restrict__ out)
{
    __shared__ short smem[19520];      // 38.1 KB
    short* s1 = smem;                  // [0, 6720): 20-row input slab (13.4 KB)
    short* s2 = smem + 6720;           // [6720, 19520): conv1-out, conv2-swizzled
    short* s3 = smem;                  // alias: conv2-out (5184 <= 6720, s1 dead)

    const int tid = threadIdx.x, img = blockIdx.x;
    const int w = tid >> 6, lane = tid & 63;
    const int row = lane & 15, g = lane >> 4;

    const float* ibase = in + (size_t)img * 28224;

    // conv1 B-frags hoisted for BOTH n-tiles (n = jn*16+row)
    bf16x8 bf1[2][8];
#pragma unroll
    for (int jn = 0; jn < 2; ++jn)
#pragma unroll
        for (int ky = 0; ky < 8; ++ky)
            bf1[jn][ky] = *reinterpret_cast<const bf16x8*>(
                wp1 + ((size_t)(ky * 4 + g) * 32 + jn * 16 + row) * 8);
    const float bva = b1[row], bvb = b1[16 + row];

    // phase staging: up to 20 rows x 84 float4 = 1680 float4; 7 per thread
    float4 pf[7];
#define LOADPH(rbase, nvec)                                                 \
    {                                                                       \
        const float4* _src = reinterpret_cast<const float4*>(               \
            ibase + (size_t)(rbase) * 336);                                 \
        _Pragma("unroll")                                                   \
        for (int j = 0; j < 7; ++j) {                                       \
            int i = tid + j * 256;                                          \
            if (i < (nvec)) pf[j] = _src[i];                                \
        }                                                                   \
    }
#define STOREPH(nvec)                                                       \
    {                                                                       \
        _Pragma("unroll")                                                   \
        for (int j = 0; j < 7; ++j) {                                       \
            int i = tid + j * 256;                                          \
            if (i < (nvec)) {                                               \
                float4 v = pf[j];                                           \
                short4v b4;                                                 \
                b4.x = f2b(v.x); b4.y = f2b(v.y);                           \
                b4.z = f2b(v.z); b4.w = f2b(v.w);                           \
                *reinterpret_cast<short4v*>(s1 + i * 4) = b4;               \
            }                                                               \
        }                                                                   \
    }

    // phase ph: tiles 4ph..4ph+3 (ph<6), tile 24 (ph=6, wave 0 only)
    // input row base: ph<=4 -> 12ph ; ph=5 -> 64 ; ph=6 -> 76 (8 rows)
    LOADPH(0, 1680)
    STOREPH(1680)
    LOADPH(12, 1680)
    __syncthreads();           // slab(0) ready

    for (int ph = 0; ph < 7; ++ph) {
        const int rbc = (ph <= 4) ? 12 * ph : ((ph == 5) ? 64 : 76);
        if (ph < 6 || w == 0) {
            const int mt = (ph < 6) ? (4 * ph + w) : 24;
            const int p = mt * 16 + row;       // 0..399
            const int y = p / 20, x = p % 20;
            const int lr0 = 4 * y - rbc;
            const short* ap = s1 + lr0 * 336 + 16 * x + 8 * g;

            f32x4 acc0 = (f32x4){0.f, 0.f, 0.f, 0.f};
            f32x4 acc1 = (f32x4){0.f, 0.f, 0.f, 0.f};
#pragma unroll
            for (int ky = 0; ky < 8; ++ky) {
                const bf16x8 af = *reinterpret_cast<const bf16x8*>(ap + ky * 336);
                acc0 = __builtin_amdgcn_mfma_f32_16x16x32_bf16(af, bf1[0][ky], acc0, 0, 0, 0);
                acc1 = __builtin_amdgcn_mfma_f32_16x16x32_bf16(af, bf1[1][ky], acc1, 0, 0, 0);
            }
#pragma unroll
            for (int r = 0; r < 4; ++r) {
                int po = mt * 16 + g * 4 + r;
                unsigned byA = (unsigned)(po * 64 + row * 2) ^ (((unsigned)(po >> 1) & 7) << 4);
                *reinterpret_cast<short*>(reinterpret_cast<char*>(s2) + byA) =
                    f2b(fmaxf(acc0[r] + bva, 0.f));
                *reinterpret_cast<short*>(reinterpret_cast<char*>(s2) + (byA ^ 32)) =
                    f2b(fmaxf(acc1[r] + bvb, 0.f));
            }
        }
        if (ph < 6) {
            __syncthreads();   // all reads of slab(ph) done
            const int nvn = (ph + 1 == 6) ? 672 : 1680;
            STOREPH(nvn)       // drain regs (phase ph+1) into slab
            if (ph < 5) {
                const int p2 = ph + 2;
                const int rb2 = (p2 <= 4) ? 12 * p2 : ((p2 == 5) ? 64 : 76);
                const int nv2 = (p2 == 6) ? 672 : 1680;
                LOADPH(rb2, nv2)
            }
            __syncthreads();   // slab(ph+1) ready
        }
    }
    __syncthreads();           // s2 complete

    // ---- conv2: M=81, N=64, K=512; wave = (n-pair, m-half); reads s2 -> s3
    {
        const int np0 = (w & 1) * 2;       // first n-tile (0 or 2)
        const int mh = w >> 1;             // m-tiles 3mh..3mh+2
        f32x4 acc[3][2];
#pragma unroll
        for (int i = 0; i < 3; ++i) {
            acc[i][0] = (f32x4){0.f, 0.f, 0.f, 0.f};
            acc[i][1] = (f32x4){0.f, 0.f, 0.f, 0.f};
        }

        int qb[3];
#pragma unroll
        for (int i = 0; i < 3; ++i) {
            int p = (3 * mh + i) * 16 + row; if (p > 80) p = 80;
            int y = p / 9, x = p - y * 9;
            qb[i] = y * 40 + x * 2;
        }

        for (int kt = 0; kt < 16; ++kt) {
            const int ky = kt >> 2, kx = kt & 3;
            const short* wb = wp2 + ((size_t)(kt * 4 + g) * 64 + np0 * 16 + row) * 8;
            const bf16x8 bA = *reinterpret_cast<const bf16x8*>(wb);
            const bf16x8 bB = *reinterpret_cast<const bf16x8*>(wb + 128);
            const int qoff = ky * 20 + kx;
#pragma unroll
            for (int i = 0; i < 3; ++i) {
                int q = qb[i] + qoff;
                unsigned byte = (unsigned)(q * 64 + g * 16) ^ ((((unsigned)q >> 1) & 7) << 4);
                const bf16x8 af = *reinterpret_cast<const bf16x8*>(
                    reinterpret_cast<const char*>(s2) + byte);
                acc[i][0] = __builtin_amdgcn_mfma_f32_16x16x32_bf16(af, bA, acc[i][0], 0, 0, 0);
                acc[i][1] = __builtin_amdgcn_mfma_f32_16x16x32_bf16(af, bB, acc[i][1], 0, 0, 0);
            }
        }

        const int n0 = np0 * 16 + row;
        const float bv0 = b2[n0], bv1 = b2[n0 + 16];
#pragma unroll
        for (int i = 0; i < 3; ++i)
#pragma unroll
            for (int r = 0; r < 4; ++r) {
                int p = (3 * mh + i) * 16 + g * 4 + r;
                if (p < 81) {
                    unsigned byte = (unsigned)(p * 128 + n0 * 2) ^ (((unsigned)p & 7) << 4);
                    *reinterpret_cast<short*>(reinterpret_cast<char*>(s3) + byte) =
                        f2b(fmaxf(acc[i][0][r] + bv0, 0.f));
                    *reinterpret_cast<short*>(reinterpret_cast<char*>(s3) + (byte ^ 32)) =
                        f2b(fmaxf(acc[i][1][r] + bv1, 0.f));
                }
            }
    }
    __syncthreads();

    // ---- conv3: M=49, N=64, K=576; wave = (n-pair, m-half); reads s3 -> global
    {
        const int np0 = (w & 1) * 2;
        const int mh = w >> 1;             // m-tiles 2mh, 2mh+1
        f32x4 acc[2][2];
#pragma unroll
        for (int i = 0; i < 2; ++i) {
            acc[i][0] = (f32x4){0.f, 0.f, 0.f, 0.f};
            acc[i][1] = (f32x4){0.f, 0.f, 0.f, 0.f};
        }

        int qb[2];
#pragma unroll
        for (int i = 0; i < 2; ++i) {
            int p = (2 * mh + i) * 16 + row; if (p > 48) p = 48;
            int y = p / 7, x = p - y * 7;
            qb[i] = y * 9 + x;
        }

        for (int kt = 0; kt < 18; ++kt) {
            const int kxy = kt >> 1;
            const int ky = kxy / 3, kx = kxy - ky * 3;
            const int coff = (kt & 1) * 64 + g * 16;
            const short* wb = wp3 + ((size_t)(kt * 4 + g) * 64 + np0 * 16 + row) * 8;
            const bf16x8 bA = *reinterpret_cast<const bf16x8*>(wb);
            const bf16x8 bB = *reinterpret_cast<const bf16x8*>(wb + 128);
            const int qoff = ky * 9 + kx;
#pragma unroll
            for (int i = 0; i < 2; ++i) {
                int q = qb[i] + qoff;
                unsigned byte = (unsigned)(q * 128 + coff) ^ (((unsigned)q & 7) << 4);
                const bf16x8 af = *reinterpret_cast<const bf16x8*>(
                    reinterpret_cast<const char*>(s3) + byte);
                acc[i][0] = __builtin_amdgcn_mfma_f32_16x16x32_bf16(af, bA, acc[i][0], 0, 0, 0);
                acc[i][1] = __builtin_amdgcn_mfma_f32_16x16x32_bf16(af, bB, acc[i][1], 0, 0, 0);
            }
        }

        const int n0 = np0 * 16 + row;
        const float bv0 = b3[n0], bv1 = b3[n0 + 16];
        short* ob = out + (size_t)img * 3136;
#pragma unroll
        for (int i = 0; i < 2; ++i)
#pragma unroll
            for (int r = 0; r < 4; ++r) {
                int p = (2 * mh + i) * 16 + g * 4 + r;
                if (p < 49) {
                    ob[p * 64 + n0]      = f2b(fmaxf(acc[i][0][r] + bv0, 0.f));
                    ob[p * 64 + n0 + 16] = f2b(fmaxf(acc[i][1][r] + bv1, 0.f));
                }
            }
    }
#undef LOADPH
#undef STOREPH
}

// ---------------- dense MFMA: feats = relu(A[2048,3136] @ W + b) -> out fp32
__global__ __launch_bounds__(512) void dense_mfma(
    const short* __restrict__ A, const short* __restrict__ wp,
    const float* __restrict__ bias, float* __restrict__ outp)
{
    const int tid = threadIdx.x;
    const int w = tid >> 6, lane = tid & 63;
    const int row = lane & 15, g = lane >> 4;
    const int bm0 = blockIdx.x * 64, bn0 = blockIdx.y * 64;
    const int nt = w & 3, mtb = (w >> 2) * 2;

    f32x4 acc0 = (f32x4){0.f, 0.f, 0.f, 0.f};
    f32x4 acc1 = (f32x4){0.f, 0.f, 0.f, 0.f};

    const short* a0 = A + (size_t)(bm0 + mtb * 16 + row) * FLAT + g * 8;
    const short* a1 = a0 + 16 * FLAT;
    const short* bp = wp + ((size_t)g * FEAT + bn0 + nt * 16 + row) * 8;

    for (int kt = 0; kt < 98; ++kt) {
        const bf16x8 b  = *reinterpret_cast<const bf16x8*>(bp + (size_t)kt * 4 * FEAT * 8);
        const bf16x8 x0 = *reinterpret_cast<const bf16x8*>(a0 + kt * 32);
        const bf16x8 x1 = *reinterpret_cast<const bf16x8*>(a1 + kt * 32);
        acc0 = __builtin_amdgcn_mfma_f32_16x16x32_bf16(x0, b, acc0, 0, 0, 0);
        acc1 = __builtin_amdgcn_mfma_f32_16x16x32_bf16(x1, b, acc1, 0, 0, 0);
    }

    const int n = bn0 + nt * 16 + row;
    const float bv = bias[n];
#pragma unroll
    for (int r = 0; r < 4; ++r) {
        int m0 = bm0 + mtb * 16 + g * 4 + r;
        outp[(size_t)m0 * OUTROW + n] = fmaxf(acc0[r] + bv, 0.f);
        int m1 = m0 + 16;
        outp[(size_t)m1 * OUTROW + n] = fmaxf(acc1[r] + bv, 0.f);
    }
}

// ---------------- mx MFMA: mx[2048,192] = feats(out fp32, stride 576) @ gru_k + bi
__global__ __launch_bounds__(512) void mx_mfma(
    const float* __restrict__ A, const short* __restrict__ wp,
    const float* __restrict__ gb, float* __restrict__ mx)
{
    const int tid = threadIdx.x;
    const int w = tid >> 6, lane = tid & 63;
    const int row = lane & 15, g = lane >> 4;
    const int bm0 = blockIdx.x * 64, bn0 = blockIdx.y * 64;
    const int nt = w & 3, mtb = (w >> 2) * 2;

    f32x4 acc0 = (f32x4){0.f, 0.f, 0.f, 0.f};
    f32x4 acc1 = (f32x4){0.f, 0.f, 0.f, 0.f};

    const float* a0 = A + (size_t)(bm0 + mtb * 16 + row) * OUTROW + g * 8;
    const float* a1 = a0 + (size_t)16 * OUTROW;
    const short* bp = wp + ((size_t)g * 192 + bn0 + nt * 16 + row) * 8;

    for (int kt = 0; kt < 16; ++kt) {
        const bf16x8 b = *reinterpret_cast<const bf16x8*>(bp + (size_t)kt * 4 * 192 * 8);
        const float4 u0 = *reinterpret_cast<const float4*>(a0 + kt * 32);
        const float4 u1 = *reinterpret_cast<const float4*>(a0 + kt * 32 + 4);
        const float4 v0 = *reinterpret_cast<const float4*>(a1 + kt * 32);
        const float4 v1 = *reinterpret_cast<const float4*>(a1 + kt * 32 + 4);
        bf16x8 x0, x1;
        x0[0] = f2b(u0.x); x0[1] = f2b(u0.y); x0[2] = f2b(u0.z); x0[3] = f2b(u0.w);
        x0[4] = f2b(u1.x); x0[5] = f2b(u1.y); x0[6] = f2b(u1.z); x0[7] = f2b(u1.w);
        x1[0] = f2b(v0.x); x1[1] = f2b(v0.y); x1[2] = f2b(v0.z); x1[3] = f2b(v0.w);
        x1[4] = f2b(v1.x); x1[5] = f2b(v1.y); x1[6] = f2b(v1.z); x1[7] = f2b(v1.w);
        acc0 = __builtin_amdgcn_mfma_f32_16x16x32_bf16(x0, b, acc0, 0, 0, 0);
        acc1 = __builtin_amdgcn_mfma_f32_16x16x32_bf16(x1, b, acc1, 0, 0, 0);
    }

    const int n = bn0 + nt * 16 + row;
    const float bv = gb[n];                 // bi row
#pragma unroll
    for (int r = 0; r < 4; ++r) {
        int m0 = bm0 + mtb * 16 + g * 4 + r;
        mx[(size_t)m0 * 192 + n] = acc0[r] + bv;
        int m1 = m0 + 16;
        mx[(size_t)m1 * 192 + n] = acc1[r] + bv;
    }
}

// ---------------- GRU segments: one wave per segment (<=16 steps, no resets inside)
__global__ __launch_bounds__(64) void gru_seg_kernel(
    const float* __restrict__ mx,     // [2048,192]
    const float* __restrict__ rk,     // [64,192]
    const float* __restrict__ gb,     // [2,192]; br = gb + 192
    const float* __restrict__ state0, // [16,64]
    const int*   __restrict__ seg, const int* __restrict__ nseg,
    float* __restrict__ out)
{
    const int b = blockIdx.x >> 7;
    const int i = blockIdx.x & 127;
    if (i >= nseg[b]) return;
    const int e = seg[b * TSTEPS + i];
    const int start = e & 255;
    const int len   = (e >> 8) & 255;
    const int rend  = (e >> 16) & 1;

    const int u = threadIdx.x;
    float h = (start == 0) ? state0[b * 64 + u] : 0.f;
    const float brz = gb[192 + u];
    const float brr = gb[192 + 64 + u];
    const float brh = gb[192 + 128 + u];

    for (int k = 0; k < len; ++k) {
        const int bt = b * TSTEPS + start + k;
        float az = 0.f, ar = 0.f, ah = 0.f;
#pragma unroll 16
        for (int j = 0; j < 64; ++j) {
            const float hj = __shfl(h, j);
            az = fmaf(hj, rk[j * 192 + u], az);
            ar = fmaf(hj, rk[j * 192 + 64 + u], ar);
            ah = fmaf(hj, rk[j * 192 + 128 + u], ah);
        }
        const float xz = mx[(size_t)bt * 192 + u];
        const float xr = mx[(size_t)bt * 192 + 64 + u];
        const float xh = mx[(size_t)bt * 192 + 128 + u];
        const float z = 1.f / (1.f + __expf(-(xz + az + brz)));
        const float r = 1.f / (1.f + __expf(-(xr + ar + brr)));
        const float hh = tanhf(xh + r * (ah + brh));
        const float hn = z * h + (1.f - z) * hh;

        out[(size_t)bt * OUTROW + 512 + u] = hn;
        h = hn;
    }

    if (start + len == TSTEPS) {
        out[OUT_FEATS + b * 64 + u] = rend ? 0.f : h;
    }
}

extern "C" void kernel_launch(void* const* d_in, const int* in_sizes, int n_in,
                              void* d_out, int out_size, void* d_ws, size_t ws_size,
                              hipStream_t stream) {
    const float* inputs = (const float*)d_in[0];
    const int*   dones  = (const int*)d_in[1];
    const float* state0 = (const float*)d_in[2];
    const int*   step0  = (const int*)d_in[3];
    const float* c1w = (const float*)d_in[4];
    const float* c1b = (const float*)d_in[5];
    const float* c2w = (const float*)d_in[6];
    const float* c2b = (const float*)d_in[7];
    const float* c3w = (const float*)d_in[8];
    const float* c3b = (const float*)d_in[9];
    const float* dw  = (const float*)d_in[10];
    const float* db  = (const float*)d_in[11];
    const float* gk  = (const float*)d_in[12];
    const float* grk = (const float*)d_in[13];
    const float* gbv = (const float*)d_in[14];

    float* out = (float*)d_out;

    // workspace carve (256 B aligned). Total ~18 MB.
    char* p = (char*)d_ws;
    auto alloc = [&](size_t bytes) {
        char* r = p; p += (bytes + 255) & ~(size_t)255; return r;
    };
    short* wp1 = (short*)alloc((size_t)8192 * 2);
    short* wp2 = (short*)alloc((size_t)32768 * 2);
    short* wp3 = (short*)alloc((size_t)36864 * 2);
    short* wpd = (short*)alloc((size_t)FLAT * FEAT * 2);
    short* wpg = (short*)alloc((size_t)FEAT * 192 * 2);
    short* c3o = (short*)alloc((size_t)NIMG * FLAT * 2);
    float* mxb = (float*)alloc((size_t)NIMG * 192 * 4);
    int*   segb = (int*)alloc((size_t)BATCH * TSTEPS * 4);
    int*   nsegb = (int*)alloc((size_t)BATCH * 4);

    // pack all weights + seg precompute, one launch
    megapack<<<625, 256, 0, stream>>>(dw, gk, c1w, c2w, c3w,
                                      wpd, wpg, wp1, wp2, wp3,
                                      dones, step0, segb, nsegb, out);

    convtower_mfma<<<NIMG, 256, 0, stream>>>(inputs, wp1, c1b, wp2, c2b, wp3, c3b, c3o);

    dim3 gd(NIMG / 64, FEAT / 64);
    dense_mfma<<<gd, 512, 0, stream>>>(c3o, wpd, db, out);

    dim3 gm(NIMG / 64, 192 / 64);
    mx_mfma<<<gm, 512, 0, stream>>>(out, wpg, gbv, mxb);

    gru_seg_kernel<<<BATCH * TSTEPS, 64, 0, stream>>>(
        mxb, grk, gbv, state0, segb, nsegb, out);
}

// Round 11
// 186.089 us; speedup vs baseline: 1.0587x; 1.0587x over previous
//
#include <hip/hip_runtime.h>
#include <math.h>

#define BATCH 16
#define TSTEPS 128
#define UNITS 64
#define FEAT 512
#define FLAT 3136
#define OUTROW 576           // 512 + 64
#define OUT_FEATS (BATCH * TSTEPS * OUTROW)   // 1179648
#define MEMN 16
#define NIMG 2048

typedef short bf16x8 __attribute__((ext_vector_type(8)));
typedef short short4v __attribute__((ext_vector_type(4)));
typedef float f32x4 __attribute__((ext_vector_type(4)));

__device__ __forceinline__ short f2b(float f) {
    unsigned u = __float_as_uint(f);
    unsigned r = (u + 0x7FFFu + ((u >> 16) & 1u)) >> 16;
    return (short)r;
}

// ---------------- mega-pack: all weight matrices fp32 [K][N] -> bf16 [K/8][N][8]
// (coalesced via LDS transpose) + seg precompute as the last block.
__global__ __launch_bounds__(256) void megapack(
    const float* __restrict__ dw, const float* __restrict__ gk,
    const float* __restrict__ c1w, const float* __restrict__ c2w,
    const float* __restrict__ c3w,
    short* __restrict__ wpd, short* __restrict__ wpg, short* __restrict__ wp1,
    short* __restrict__ wp2, short* __restrict__ wp3,
    const int* __restrict__ dones, const int* __restrict__ step0,
    int* __restrict__ seg, int* __restrict__ nseg, float* __restrict__ out)
{
    __shared__ float lds[8 * 513];         // 16.4 KB, pad 513 -> conflict-free
    const int blk = blockIdx.x;
    const int tid = threadIdx.x;

    const float* src; short* dst; int N, kg;
    if (blk < 392)      { src = dw;  dst = wpd; N = 512; kg = blk; }
    else if (blk < 456) { src = gk;  dst = wpg; N = 192; kg = blk - 392; }
    else if (blk < 488) { src = c1w; dst = wp1; N = 32;  kg = blk - 456; }
    else if (blk < 552) { src = c2w; dst = wp2; N = 64;  kg = blk - 488; }
    else if (blk < 624) { src = c3w; dst = wp3; N = 64;  kg = blk - 552; }
    else {
        // segment precompute: step dynamics depend only on dones/step0
        const int b = tid;
        if (b < BATCH) {
            int step = step0[b];
            int n = 0, start = 0;
            for (int t = 0; t < TSTEPS; ++t) {
                step += 1;
                const int reset = (dones[b * TSTEPS + t] == 1) || ((step % MEMN) == 0);
                if (reset) step = 0;
                if (reset || t == TSTEPS - 1) {
                    seg[b * TSTEPS + n] = start | ((t - start + 1) << 8) | (reset << 16);
                    n += 1;
                    start = t + 1;
                }
            }
            nseg[b] = n;
            out[OUT_FEATS + 1024 + b] = (float)step;
        }
        return;
    }

#pragma unroll
    for (int j = 0; j < 8; ++j)
        for (int n = tid; n < N; n += 256)
            lds[j * 513 + n] = src[(size_t)(kg * 8 + j) * N + n];
    __syncthreads();
    short* d = dst + (size_t)kg * N * 8;
    for (int t = tid; t < N * 8; t += 256) {
        int n = t >> 3, j = t & 7;
        d[t] = f2b(lds[j * 513 + n]);
    }
}

// ---------------- fused conv tower: in [n,84,84,4] fp32 -> out [n,3136] bf16
// One block per image, 256 thr = 4 waves, 38.1 KB LDS -> 4 blocks/CU.
// conv1: 5 phases x 4 output rows (5 m-tiles), single 20-row slab + REGISTER
// PREFETCH of the next phase (async-STAGE split: loads issued before compute,
// drained to LDS after the barrier). conv2 -> s3 (aliases slab). conv3 -> global.
__global__ __launch_bounds__(256) void convtower_mfma(
    const float* __restrict__ in,
    const short* __restrict__ wp1, const float* __restrict__ b1,
    const short* __restrict__ wp2, const float* __restrict__ b2,
    const short* __restrict__ wp3, const float* __restrict__ b3,
    short* __restrict__ out)
{
    __shared__ short smem[19520];      // 38.1 KB
    short* s1 = smem;                  // [0, 6720): 20-row input slab (13.4 KB)
    short* s2 = smem + 6720;           // [6720, 19520): conv1-out, conv2-swizzled
    short* s3 = smem;                  // alias: conv2-out (5184 <= 6720, s1 dead)

    const int tid = threadIdx.x, img = blockIdx.x;
    const int w = tid >> 6, lane = tid & 63;
    const int row = lane & 15, g = lane >> 4;
    const int wn = w & 1, wm = w >> 1;     // conv1: n-tile, m-parity

    const float* ibase = in + (size_t)img * 28224;

    // conv1 B-frags hoisted (8 ky)
    bf16x8 bf1[8];
#pragma unroll
    for (int ky = 0; ky < 8; ++ky)
        bf1[ky] = *reinterpret_cast<const bf16x8*>(
            wp1 + ((size_t)(ky * 4 + g) * 32 + wn * 16 + row) * 8);
    const float bv1 = b1[wn * 16 + row];
    const int n1 = wn * 16 + row;

    // phase staging: 20 rows x 84 float4 = 1680 float4; 7 per thread
    float4 pf[7];
#define LOADPH(ph)                                                          \
    {                                                                       \
        const float4* _src = reinterpret_cast<const float4*>(               \
            ibase + (size_t)(ph) * 16 * 336);                               \
        _Pragma("unroll")                                                   \
        for (int j = 0; j < 7; ++j) {                                       \
            int i = tid + j * 256;                                          \
            if (i < 1680) pf[j] = _src[i];                                  \
        }                                                                   \
    }
#define STOREPH()                                                           \
    {                                                                       \
        _Pragma("unroll")                                                   \
        for (int j = 0; j < 7; ++j) {                                       \
            int i = tid + j * 256;                                          \
            if (i < 1680) {                                                 \
                float4 v = pf[j];                                           \
                short4v b4;                                                 \
                b4.x = f2b(v.x); b4.y = f2b(v.y);                           \
                b4.z = f2b(v.z); b4.w = f2b(v.w);                           \
                *reinterpret_cast<short4v*>(s1 + i * 4) = b4;               \
            }                                                               \
        }                                                                   \
    }

    LOADPH(0);
    STOREPH();
    LOADPH(1);                 // in flight across phase-0 compute
    __syncthreads();           // slab(0) ready

    for (int ph = 0; ph < 5; ++ph) {
        // compute m-tiles [5ph, 5ph+5), this wave: parity wm
        for (int mt = 5 * ph + wm; mt < 5 * ph + 5; mt += 2) {
            const int p = mt * 16 + row;       // 0..399
            const int y = p / 20, x = p % 20;
            const int lr0 = 4 * y - 16 * ph;   // 0,4,8,12
            const short* ap = s1 + lr0 * 336 + 16 * x + 8 * g;

            f32x4 acc = (f32x4){0.f, 0.f, 0.f, 0.f};
#pragma unroll
            for (int ky = 0; ky < 8; ++ky) {
                const bf16x8 af = *reinterpret_cast<const bf16x8*>(ap + ky * 336);
                acc = __builtin_amdgcn_mfma_f32_16x16x32_bf16(af, bf1[ky], acc, 0, 0, 0);
            }
#pragma unroll
            for (int r = 0; r < 4; ++r) {
                int po = mt * 16 + g * 4 + r;
                unsigned byte = (unsigned)(po * 64 + n1 * 2);
                byte ^= ((po >> 1) & 7) << 4;
                *reinterpret_cast<short*>(reinterpret_cast<char*>(s2) + byte) =
                    f2b(fmaxf(acc[r] + bv1, 0.f));
            }
        }
        if (ph < 4) {
            __syncthreads();   // all reads of slab(ph) done
            STOREPH();         // drain regs (phase ph+1) into slab
            if (ph < 3) LOADPH(ph + 2);   // issue next loads; hide under ph+1 compute
            __syncthreads();   // slab(ph+1) ready
        }
    }
    __syncthreads();           // s2 complete

    // ---- conv2: M=81 (6 m-tiles), N=64, K=512; reads s2, writes s3 (swizzled)
    {
        f32x4 acc[6];
#pragma unroll
        for (int i = 0; i < 6; ++i) acc[i] = (f32x4){0.f, 0.f, 0.f, 0.f};

        int qb[6];
#pragma unroll
        for (int mt = 0; mt < 6; ++mt) {
            int p = mt * 16 + row; if (p > 80) p = 80;
            int y = p / 9, x = p % 9;
            qb[mt] = y * 40 + x * 2;
        }

        for (int kt = 0; kt < 16; ++kt) {
            const int ky = kt >> 2, kx = kt & 3;
            const bf16x8 bfrag = *reinterpret_cast<const bf16x8*>(
                wp2 + ((size_t)(kt * 4 + g) * 64 + w * 16 + row) * 8);
            const int qoff = ky * 20 + kx;
#pragma unroll
            for (int mt = 0; mt < 6; ++mt) {
                int q = qb[mt] + qoff;
                unsigned byte = (unsigned)(q * 64 + g * 16);
                byte ^= ((q >> 1) & 7) << 4;
                const bf16x8 af = *reinterpret_cast<const bf16x8*>(
                    reinterpret_cast<const char*>(s2) + byte);
                acc[mt] = __builtin_amdgcn_mfma_f32_16x16x32_bf16(af, bfrag, acc[mt], 0, 0, 0);
            }
        }

        const int n = w * 16 + row;
        const float bv = b2[n];
#pragma unroll
        for (int mt = 0; mt < 6; ++mt)
#pragma unroll
            for (int r = 0; r < 4; ++r) {
                int p = mt * 16 + g * 4 + r;
                if (p < 81) {
                    unsigned byte = (unsigned)(p * 128 + n * 2);
                    byte ^= (p & 7) << 4;
                    *reinterpret_cast<short*>(reinterpret_cast<char*>(s3) + byte) =
                        f2b(fmaxf(acc[mt][r] + bv, 0.f));
                }
            }
    }
    __syncthreads();

    // ---- conv3: M=49 (4 m-tiles), N=64, K=576; reads s3, writes global
    {
        f32x4 acc[4];
#pragma unroll
        for (int i = 0; i < 4; ++i) acc[i] = (f32x4){0.f, 0.f, 0.f, 0.f};

        int qb[4];
#pragma unroll
        for (int mt = 0; mt < 4; ++mt) {
            int p = mt * 16 + row; if (p > 48) p = 48;
            int y = p / 7, x = p % 7;
            qb[mt] = y * 9 + x;
        }

        for (int kt = 0; kt < 18; ++kt) {
            const int kxy = kt >> 1;
            const int ky = kxy / 3, kx = kxy - ky * 3;
            const int coff = (kt & 1) * 64 + g * 16;
            const bf16x8 bfrag = *reinterpret_cast<const bf16x8*>(
                wp3 + ((size_t)(kt * 4 + g) * 64 + w * 16 + row) * 8);
            const int qoff = ky * 9 + kx;
#pragma unroll
            for (int mt = 0; mt < 4; ++mt) {
                int q = qb[mt] + qoff;
                unsigned byte = (unsigned)(q * 128 + coff);
                byte ^= (q & 7) << 4;
                const bf16x8 af = *reinterpret_cast<const bf16x8*>(
                    reinterpret_cast<const char*>(s3) + byte);
                acc[mt] = __builtin_amdgcn_mfma_f32_16x16x32_bf16(af, bfrag, acc[mt], 0, 0, 0);
            }
        }

        const int n = w * 16 + row;
        const float bv = b3[n];
        short* ob = out + (size_t)img * 3136;
#pragma unroll
        for (int mt = 0; mt < 4; ++mt)
#pragma unroll
            for (int r = 0; r < 4; ++r) {
                int p = mt * 16 + g * 4 + r;
                if (p < 49) ob[p * 64 + n] = f2b(fmaxf(acc[mt][r] + bv, 0.f));
            }
    }
#undef LOADPH
#undef STOREPH
}

// ---------------- dense MFMA: feats = relu(A[2048,3136] @ W + b) -> out fp32
__global__ __launch_bounds__(512) void dense_mfma(
    const short* __restrict__ A, const short* __restrict__ wp,
    const float* __restrict__ bias, float* __restrict__ outp)
{
    const int tid = threadIdx.x;
    const int w = tid >> 6, lane = tid & 63;
    const int row = lane & 15, g = lane >> 4;
    const int bm0 = blockIdx.x * 64, bn0 = blockIdx.y * 64;
    const int nt = w & 3, mtb = (w >> 2) * 2;

    f32x4 acc0 = (f32x4){0.f, 0.f, 0.f, 0.f};
    f32x4 acc1 = (f32x4){0.f, 0.f, 0.f, 0.f};

    const short* a0 = A + (size_t)(bm0 + mtb * 16 + row) * FLAT + g * 8;
    const short* a1 = a0 + 16 * FLAT;
    const short* bp = wp + ((size_t)g * FEAT + bn0 + nt * 16 + row) * 8;

    for (int kt = 0; kt < 98; ++kt) {
        const bf16x8 b  = *reinterpret_cast<const bf16x8*>(bp + (size_t)kt * 4 * FEAT * 8);
        const bf16x8 x0 = *reinterpret_cast<const bf16x8*>(a0 + kt * 32);
        const bf16x8 x1 = *reinterpret_cast<const bf16x8*>(a1 + kt * 32);
        acc0 = __builtin_amdgcn_mfma_f32_16x16x32_bf16(x0, b, acc0, 0, 0, 0);
        acc1 = __builtin_amdgcn_mfma_f32_16x16x32_bf16(x1, b, acc1, 0, 0, 0);
    }

    const int n = bn0 + nt * 16 + row;
    const float bv = bias[n];
#pragma unroll
    for (int r = 0; r < 4; ++r) {
        int m0 = bm0 + mtb * 16 + g * 4 + r;
        outp[(size_t)m0 * OUTROW + n] = fmaxf(acc0[r] + bv, 0.f);
        int m1 = m0 + 16;
        outp[(size_t)m1 * OUTROW + n] = fmaxf(acc1[r] + bv, 0.f);
    }
}

// ---------------- mx MFMA: mx[2048,192] = feats(out fp32, stride 576) @ gru_k + bi
__global__ __launch_bounds__(512) void mx_mfma(
    const float* __restrict__ A, const short* __restrict__ wp,
    const float* __restrict__ gb, float* __restrict__ mx)
{
    const int tid = threadIdx.x;
    const int w = tid >> 6, lane = tid & 63;
    const int row = lane & 15, g = lane >> 4;
    const int bm0 = blockIdx.x * 64, bn0 = blockIdx.y * 64;
    const int nt = w & 3, mtb = (w >> 2) * 2;

    f32x4 acc0 = (f32x4){0.f, 0.f, 0.f, 0.f};
    f32x4 acc1 = (f32x4){0.f, 0.f, 0.f, 0.f};

    const float* a0 = A + (size_t)(bm0 + mtb * 16 + row) * OUTROW + g * 8;
    const float* a1 = a0 + (size_t)16 * OUTROW;
    const short* bp = wp + ((size_t)g * 192 + bn0 + nt * 16 + row) * 8;

    for (int kt = 0; kt < 16; ++kt) {
        const bf16x8 b = *reinterpret_cast<const bf16x8*>(bp + (size_t)kt * 4 * 192 * 8);
        const float4 u0 = *reinterpret_cast<const float4*>(a0 + kt * 32);
        const float4 u1 = *reinterpret_cast<const float4*>(a0 + kt * 32 + 4);
        const float4 v0 = *reinterpret_cast<const float4*>(a1 + kt * 32);
        const float4 v1 = *reinterpret_cast<const float4*>(a1 + kt * 32 + 4);
        bf16x8 x0, x1;
        x0[0] = f2b(u0.x); x0[1] = f2b(u0.y); x0[2] = f2b(u0.z); x0[3] = f2b(u0.w);
        x0[4] = f2b(u1.x); x0[5] = f2b(u1.y); x0[6] = f2b(u1.z); x0[7] = f2b(u1.w);
        x1[0] = f2b(v0.x); x1[1] = f2b(v0.y); x1[2] = f2b(v0.z); x1[3] = f2b(v0.w);
        x1[4] = f2b(v1.x); x1[5] = f2b(v1.y); x1[6] = f2b(v1.z); x1[7] = f2b(v1.w);
        acc0 = __builtin_amdgcn_mfma_f32_16x16x32_bf16(x0, b, acc0, 0, 0, 0);
        acc1 = __builtin_amdgcn_mfma_f32_16x16x32_bf16(x1, b, acc1, 0, 0, 0);
    }

    const int n = bn0 + nt * 16 + row;
    const float bv = gb[n];                 // bi row
#pragma unroll
    for (int r = 0; r < 4; ++r) {
        int m0 = bm0 + mtb * 16 + g * 4 + r;
        mx[(size_t)m0 * 192 + n] = acc0[r] + bv;
        int m1 = m0 + 16;
        mx[(size_t)m1 * 192 + n] = acc1[r] + bv;
    }
}

// ---------------- GRU segments: one wave per segment (<=16 steps, no resets inside)
__global__ __launch_bounds__(64) void gru_seg_kernel(
    const float* __restrict__ mx,     // [2048,192]
    const float* __restrict__ rk,     // [64,192]
    const float* __restrict__ gb,     // [2,192]; br = gb + 192
    const float* __restrict__ state0, // [16,64]
    const int*   __restrict__ seg, const int* __restrict__ nseg,
    float* __restrict__ out)
{
    const int b = blockIdx.x >> 7;
    const int i = blockIdx.x & 127;
    if (i >= nseg[b]) return;
    const int e = seg[b * TSTEPS + i];
    const int start = e & 255;
    const int len   = (e >> 8) & 255;
    const int rend  = (e >> 16) & 1;

    const int u = threadIdx.x;
    float h = (start == 0) ? state0[b * 64 + u] : 0.f;
    const float brz = gb[192 + u];
    const float brr = gb[192 + 64 + u];
    const float brh = gb[192 + 128 + u];

    for (int k = 0; k < len; ++k) {
        const int bt = b * TSTEPS + start + k;
        float az = 0.f, ar = 0.f, ah = 0.f;
#pragma unroll 16
        for (int j = 0; j < 64; ++j) {
            const float hj = __shfl(h, j);
            az = fmaf(hj, rk[j * 192 + u], az);
            ar = fmaf(hj, rk[j * 192 + 64 + u], ar);
            ah = fmaf(hj, rk[j * 192 + 128 + u], ah);
        }
        const float xz = mx[(size_t)bt * 192 + u];
        const float xr = mx[(size_t)bt * 192 + 64 + u];
        const float xh = mx[(size_t)bt * 192 + 128 + u];
        const float z = 1.f / (1.f + __expf(-(xz + az + brz)));
        const float r = 1.f / (1.f + __expf(-(xr + ar + brr)));
        const float hh = tanhf(xh + r * (ah + brh));
        const float hn = z * h + (1.f - z) * hh;

        out[(size_t)bt * OUTROW + 512 + u] = hn;
        h = hn;
    }

    if (start + len == TSTEPS) {
        out[OUT_FEATS + b * 64 + u] = rend ? 0.f : h;
    }
}

extern "C" void kernel_launch(void* const* d_in, const int* in_sizes, int n_in,
                              void* d_out, int out_size, void* d_ws, size_t ws_size,
                              hipStream_t stream) {
    const float* inputs = (const float*)d_in[0];
    const int*   dones  = (const int*)d_in[1];
    const float* state0 = (const float*)d_in[2];
    const int*   step0  = (const int*)d_in[3];
    const float* c1w = (const float*)d_in[4];
    const float* c1b = (const float*)d_in[5];
    const float* c2w = (const float*)d_in[6];
    const float* c2b = (const float*)d_in[7];
    const float* c3w = (const float*)d_in[8];
    const float* c3b = (const float*)d_in[9];
    const float* dw  = (const float*)d_in[10];
    const float* db  = (const float*)d_in[11];
    const float* gk  = (const float*)d_in[12];
    const float* grk = (const float*)d_in[13];
    const float* gbv = (const float*)d_in[14];

    float* out = (float*)d_out;

    // workspace carve (256 B aligned). Total ~18 MB.
    char* p = (char*)d_ws;
    auto alloc = [&](size_t bytes) {
        char* r = p; p += (bytes + 255) & ~(size_t)255; return r;
    };
    short* wp1 = (short*)alloc((size_t)8192 * 2);
    short* wp2 = (short*)alloc((size_t)32768 * 2);
    short* wp3 = (short*)alloc((size_t)36864 * 2);
    short* wpd = (short*)alloc((size_t)FLAT * FEAT * 2);
    short* wpg = (short*)alloc((size_t)FEAT * 192 * 2);
    short* c3o = (short*)alloc((size_t)NIMG * FLAT * 2);
    float* mxb = (float*)alloc((size_t)NIMG * 192 * 4);
    int*   segb = (int*)alloc((size_t)BATCH * TSTEPS * 4);
    int*   nsegb = (int*)alloc((size_t)BATCH * 4);

    // pack all weights + seg precompute, one launch
    megapack<<<625, 256, 0, stream>>>(dw, gk, c1w, c2w, c3w,
                                      wpd, wpg, wp1, wp2, wp3,
                                      dones, step0, segb, nsegb, out);

    convtower_mfma<<<NIMG, 256, 0, stream>>>(inputs, wp1, c1b, wp2, c2b, wp3, c3b, c3o);

    dim3 gd(NIMG / 64, FEAT / 64);
    dense_mfma<<<gd, 512, 0, stream>>>(c3o, wpd, db, out);

    dim3 gm(NIMG / 64, 192 / 64);
    mx_mfma<<<gm, 512, 0, stream>>>(out, wpg, gbv, mxb);

    gru_seg_kernel<<<BATCH * TSTEPS, 64, 0, stream>>>(
        mxb, grk, gbv, state0, segb, nsegb, out);
}